// Round 10
// baseline (42.784 us; speedup 1.0000x reference)
//
#include <hip/hip_runtime.h>
#include <hip/hip_bf16.h>

// out[b, i*4+p, j*4+q] = sum_k w[p*4+q][k] * patch(b,i,j)[k],  k = kh*16+kw
// MFMA 16x16x32 bf16, A = weights (regs), B = patches loaded DIRECTLY from global.
// R10 = R9 with the bit_cast-on-__hip_bfloat162 build break fixed via memcpy.
// Ring-4 software pipeline at quarter-tile (K=64 = 4 loads, 2 MFMA) granularity:
//   steady state keeps 3 quarter-buffers (12 global_load_dwordx4) in flight per wave.
// Block: 256 thr / 4 waves; wave wv owns patch rows it*16+wv*4..+3, 16 patch cols.

typedef __attribute__((ext_vector_type(8))) short short8;
typedef __attribute__((ext_vector_type(4))) float f32x4;

__device__ __forceinline__ unsigned pkrn(float a, float b) {
    __hip_bfloat162 h = __float22bfloat162_rn(make_float2(a, b));
    unsigned r;
    __builtin_memcpy(&r, &h, 4);   // lo16 = bf16(a), hi16 = bf16(b)
    return r;
}

__device__ __forceinline__ short8 cvt8(float4 v0, float4 v1) {
    uint4 u = make_uint4(pkrn(v0.x, v0.y), pkrn(v0.z, v0.w),
                         pkrn(v1.x, v1.y), pkrn(v1.z, v1.w));
    return __builtin_bit_cast(short8, u);
}

__global__ __launch_bounds__(256, 4)
void conv_ring(const float* __restrict__ x,
               const float* __restrict__ w,
               float* __restrict__ out) {
    const int tid  = threadIdx.x;
    const int lane = tid & 63;
    const int wv   = tid >> 6;
    const int bx   = blockIdx.x;
    const int jt   = bx & 7;            // j-tile: patch cols jt*16..+15
    const int it   = bx >> 3;           // i-tile: patch rows it*16..+15
    const int b    = blockIdx.y;

    const float* xb = x + (size_t)b * (1024 * 1024);

    const int m  = lane & 15;           // patch col within tile (and o for weights)
    const int kb = (lane >> 4) & 1;     // kw block
    const int hi = lane >> 5;           // kh parity
    const int p  = lane >> 4;           // output sub-row in epilogue

    // weight fragments (A operand): lane holds w[o=lane&15][s*32+(lane>>4)*8+r]
    short8 wfrag[8];
    #pragma unroll
    for (int s = 0; s < 8; ++s) {
        const float* wp = w + m * 256 + s * 32 + (lane >> 4) * 8;
        wfrag[s] = cvt8(*(const float4*)wp, *(const float4*)(wp + 4));
    }

    int colf = jt * 128 + m * 8 + kb * 8;
    if (colf > 1016) colf = 1016;            // edge clamp (jp==127 lanes, store-masked)
    const int jp    = jt * 16 + m;
    const int iband = it * 16 + wv * 4;

    // step k (k=0..15): tile t=k>>2, quarter q=k&3 -> K-slices s=2q,2q+1
    // rows r0(t)+hi+4q and r0(t)+hi+4q+2, 2 float4 each.
#define ISSUE(B, k) do {                                                     \
        const int _t = (k) >> 2, _q = (k) & 3;                               \
        int _r0 = (iband + _t) * 8; if (_r0 > 1008) _r0 = 1008;              \
        const float* _p0 = xb + (size_t)(_r0 + hi + 4 * _q) * 1024 + colf;   \
        B[0] = *(const float4*)_p0;          B[1] = *(const float4*)(_p0 + 4);        \
        B[2] = *(const float4*)(_p0 + 2048); B[3] = *(const float4*)(_p0 + 2048 + 4); \
    } while (0)

#define COMP(B, k) do {                                                      \
        const int _q = (k) & 3;                                              \
        acc = __builtin_amdgcn_mfma_f32_16x16x32_bf16(                       \
                  wfrag[2 * _q],     cvt8(B[0], B[1]), acc, 0, 0, 0);        \
        acc = __builtin_amdgcn_mfma_f32_16x16x32_bf16(                       \
                  wfrag[2 * _q + 1], cvt8(B[2], B[3]), acc, 0, 0, 0);        \
    } while (0)

#define STORE(t) do {                                                        \
        const int _ip = iband + (t);                                         \
        if (_ip < 127 && jp < 127) {                                         \
            float* _op = out + (size_t)b * (508 * 508)                       \
                             + (_ip * 4 + p) * 508 + jp * 4;                 \
            *(float4*)_op = *(float4*)&acc;                                  \
        }                                                                    \
        acc = (f32x4){0.f, 0.f, 0.f, 0.f};                                   \
    } while (0)

    float4 Q0[4], Q1[4], Q2[4], Q3[4];
    f32x4 acc = {0.f, 0.f, 0.f, 0.f};

    ISSUE(Q0, 0); ISSUE(Q1, 1); ISSUE(Q2, 2);      // 3 quarters in flight

    COMP(Q0, 0);   ISSUE(Q3, 3);
    COMP(Q1, 1);   ISSUE(Q0, 4);
    COMP(Q2, 2);   ISSUE(Q1, 5);
    COMP(Q3, 3);   ISSUE(Q2, 6);   STORE(0);
    COMP(Q0, 4);   ISSUE(Q3, 7);
    COMP(Q1, 5);   ISSUE(Q0, 8);
    COMP(Q2, 6);   ISSUE(Q1, 9);
    COMP(Q3, 7);   ISSUE(Q2, 10);  STORE(1);
    COMP(Q0, 8);   ISSUE(Q3, 11);
    COMP(Q1, 9);   ISSUE(Q0, 12);
    COMP(Q2, 10);  ISSUE(Q1, 13);
    COMP(Q3, 11);  ISSUE(Q2, 14);  STORE(2);
    COMP(Q0, 12);  ISSUE(Q3, 15);
    COMP(Q1, 13);
    COMP(Q2, 14);
    COMP(Q3, 15);  STORE(3);

#undef ISSUE
#undef COMP
#undef STORE
}

extern "C" void kernel_launch(void* const* d_in, const int* in_sizes, int n_in,
                              void* d_out, int out_size, void* d_ws, size_t ws_size,
                              hipStream_t stream) {
    const float* x = (const float*)d_in[0];
    const float* w = (const float*)d_in[1];
    float* out = (float*)d_out;
    dim3 grid(64, 32);   // (it*8 + jt, batch)
    conv_ring<<<grid, dim3(256, 1, 1), 0, stream>>>(x, w, out);
}

// Round 11
// 40.853 us; speedup vs baseline: 1.0473x; 1.0473x over previous
//
#include <hip/hip_runtime.h>
#include <hip/hip_bf16.h>

// out[b, i*4+p, j*4+q] = sum_k w[p*4+q][k] * patch(b,i,j)[k],  k = kh*16+kw
// MFMA 16x16x32 bf16, A = weights (regs), B = patches loaded DIRECTLY from global.
// R11 = persistent blocks: 512 blocks (2/CU); block owns one (b, i-band) row-band
// and sweeps 4 j-tiles; ring-4 quarter pipeline stays primed ACROSS tile seams
// (steps 13-15 of tile s issue quarters 0-2 of tile s+1). Weights converted once.
// Block: 256 thr / 4 waves; wave wv owns patch rows it*16+wv*4..+3, 16 patch cols.

typedef __attribute__((ext_vector_type(8))) short short8;
typedef __attribute__((ext_vector_type(4))) float f32x4;

__device__ __forceinline__ unsigned pkrn(float a, float b) {
    __hip_bfloat162 h = __float22bfloat162_rn(make_float2(a, b));
    unsigned r;
    __builtin_memcpy(&r, &h, 4);   // lo16 = bf16(a), hi16 = bf16(b)
    return r;
}

__device__ __forceinline__ short8 cvt8(float4 v0, float4 v1) {
    uint4 u = make_uint4(pkrn(v0.x, v0.y), pkrn(v0.z, v0.w),
                         pkrn(v1.x, v1.y), pkrn(v1.z, v1.w));
    return __builtin_bit_cast(short8, u);
}

__global__ __launch_bounds__(256, 2)
void conv_persist(const float* __restrict__ x,
                  const float* __restrict__ w,
                  float* __restrict__ out) {
    const int tid  = threadIdx.x;
    const int lane = tid & 63;
    const int wv   = tid >> 6;
    const int band = blockIdx.x >> 1;       // 0..255 = b*8 + it
    const int half = blockIdx.x & 1;        // j half (4 tiles each)
    const int b    = band >> 3;
    const int it   = band & 7;

    const float* xb = x + (size_t)b * (1024 * 1024);
    float* ob = out + (size_t)b * (508 * 508);

    const int m  = lane & 15;           // patch col within tile (and o for weights)
    const int kb = (lane >> 4) & 1;     // kw block
    const int hi = lane >> 5;           // kh parity
    const int p  = lane >> 4;           // output sub-row in epilogue
    const int iband = it * 16 + wv * 4;

    // weight fragments (A operand): lane holds w[o=lane&15][s*32+(lane>>4)*8+r]
    short8 wfrag[8];
    #pragma unroll
    for (int s = 0; s < 8; ++s) {
        const float* wp = w + m * 256 + s * 32 + (lane >> 4) * 8;
        wfrag[s] = cvt8(*(const float4*)wp, *(const float4*)(wp + 4));
    }

    // quarter (k, jt): tile-local quarter k=0..15 -> t=k>>2 (patch row), q=k&3.
#define COLF(jt) ({ int _c = (jt) * 128 + m * 8 + kb * 8; if (_c > 1016) _c = 1016; _c; })

#define ISSUE(B, k, jt) do {                                                 \
        const int _t = (k) >> 2, _q = (k) & 3;                               \
        int _r0 = (iband + _t) * 8; if (_r0 > 1008) _r0 = 1008;              \
        const float* _p0 = xb + (size_t)(_r0 + hi + 4 * _q) * 1024 + COLF(jt); \
        B[0] = *(const float4*)_p0;          B[1] = *(const float4*)(_p0 + 4);        \
        B[2] = *(const float4*)(_p0 + 2048); B[3] = *(const float4*)(_p0 + 2048 + 4); \
    } while (0)

#define COMP(B, k) do {                                                      \
        const int _q = (k) & 3;                                              \
        acc = __builtin_amdgcn_mfma_f32_16x16x32_bf16(                       \
                  wfrag[2 * _q],     cvt8(B[0], B[1]), acc, 0, 0, 0);        \
        acc = __builtin_amdgcn_mfma_f32_16x16x32_bf16(                       \
                  wfrag[2 * _q + 1], cvt8(B[2], B[3]), acc, 0, 0, 0);        \
    } while (0)

#define STORE(t, jt) do {                                                    \
        const int _ip = iband + (t);                                         \
        const int _jp = (jt) * 16 + m;                                       \
        if (_ip < 127 && _jp < 127) {                                        \
            float* _op = ob + (_ip * 4 + p) * 508 + _jp * 4;                 \
            *(float4*)_op = *(float4*)&acc;                                  \
        }                                                                    \
        acc = (f32x4){0.f, 0.f, 0.f, 0.f};                                   \
    } while (0)

    float4 Q0[4], Q1[4], Q2[4], Q3[4];
    f32x4 acc = {0.f, 0.f, 0.f, 0.f};

    {   // prime with quarters 0..2 of first tile
        const int jt0 = half * 4;
        ISSUE(Q0, 0, jt0); ISSUE(Q1, 1, jt0); ISSUE(Q2, 2, jt0);
    }

    #pragma unroll
    for (int s = 0; s < 4; ++s) {
        const int jt = half * 4 + s;
        const int sn = (s < 3) ? s + 1 : 3;       // next tile (clamped; tail re-fetch harmless)
        const int jn = half * 4 + sn;

        COMP(Q0, 0);   ISSUE(Q3, 3,  jt);
        COMP(Q1, 1);   ISSUE(Q0, 4,  jt);
        COMP(Q2, 2);   ISSUE(Q1, 5,  jt);
        COMP(Q3, 3);   ISSUE(Q2, 6,  jt);  STORE(0, jt);
        COMP(Q0, 4);   ISSUE(Q3, 7,  jt);
        COMP(Q1, 5);   ISSUE(Q0, 8,  jt);
        COMP(Q2, 6);   ISSUE(Q1, 9,  jt);
        COMP(Q3, 7);   ISSUE(Q2, 10, jt);  STORE(1, jt);
        COMP(Q0, 8);   ISSUE(Q3, 11, jt);
        COMP(Q1, 9);   ISSUE(Q0, 12, jt);
        COMP(Q2, 10);  ISSUE(Q1, 13, jt);
        COMP(Q3, 11);  ISSUE(Q2, 14, jt);  STORE(2, jt);
        COMP(Q0, 12);  ISSUE(Q3, 15, jt);
        COMP(Q1, 13);  ISSUE(Q0, 0,  jn);   // keep ring full across the seam
        COMP(Q2, 14);  ISSUE(Q1, 1,  jn);
        COMP(Q3, 15);  ISSUE(Q2, 2,  jn);  STORE(3, jt);
    }

#undef COLF
#undef ISSUE
#undef COMP
#undef STORE
}

extern "C" void kernel_launch(void* const* d_in, const int* in_sizes, int n_in,
                              void* d_out, int out_size, void* d_ws, size_t ws_size,
                              hipStream_t stream) {
    const float* x = (const float*)d_in[0];
    const float* w = (const float*)d_in[1];
    float* out = (float*)d_out;
    conv_persist<<<dim3(512, 1, 1), dim3(256, 1, 1), 0, stream>>>(x, w, out);
}